// Round 23
// baseline (211.385 us; speedup 1.0000x reference)
//
#include <hip/hip_runtime.h>
#include <math.h>

#define B_ 256
#define S_ 50
#define K_ 20
#define D_ 128
#define G3 384          // 3*D
#define M_  (B_ * S_)   // 12800 (b,s) rows
#define GROWS 16        // batch rows per GRU block
#define KT 4            // k-tiles (32 wide): 128

typedef __attribute__((ext_vector_type(8))) short bf16x8;
typedef __attribute__((ext_vector_type(4))) float f32x4;

__device__ inline unsigned short bf16_rne(float f) {
    unsigned u = __float_as_uint(f);
    return (unsigned short)((u + 0x7fffu + ((u >> 16) & 1u)) >> 16);
}
__device__ inline float fsig(float x) {
    return __builtin_amdgcn_rcpf(1.f + __expf(-x));
}
__device__ inline float ftanh(float x) {
    float t = __expf(-2.f * fabsf(x));
    float r = (1.f - t) * __builtin_amdgcn_rcpf(1.f + t);
    return x >= 0.f ? r : -r;
}

#define WG_SYNC_LDS() do { \
    __builtin_amdgcn_sched_barrier(0); \
    asm volatile("s_waitcnt lgkmcnt(0)" ::: "memory"); \
    __builtin_amdgcn_s_barrier(); \
    __builtin_amdgcn_sched_barrier(0); \
} while (0)

// ---------------------------------------------------------------------------
// Kernel F (v13): FUSED pool + w_ih-cvt + MFMA GEMM. 100 blocks x 256 thr.
// Phase 1: gather-pool 128 (b,s)-rows straight into swizzled LDS A (bf16) —
//          no pooled_bf global round-trip, no separate cvt kernel/launch.
// Phase 2: for bn=0..2, stage w_ih tile f32->bf16 inline, 64 MFMA/wave,
//          bias (+b_hh folded for r/z gates only), coalesced gx[row][n] out.
// ---------------------------------------------------------------------------
__global__ __launch_bounds__(256) void pool_gemm_mfma(
    const int* __restrict__ items, const int* __restrict__ basket_len,
    const int* __restrict__ lengths, const float* __restrict__ encode,
    const float* __restrict__ w_ih, const float* __restrict__ b_ih,
    const float* __restrict__ b_hh, float* __restrict__ gx)
{
    __shared__ unsigned short Al[128 * 128];   // [m][k] swizzled, 32KB
    __shared__ unsigned short Bl[128 * 128];   // [n][k] swizzled, 32KB

    const int tid  = threadIdx.x;
    const int m0   = blockIdx.x * 128;
    const int lane = tid & 63;
    const int wv   = tid >> 6;                 // 0..3
    const int frow = lane & 15;
    const int fhi  = lane >> 4;
    const int mh   = (wv & 1) * 64;
    const int nh   = (wv >> 1) * 64;

    // ---- phase 1: pool 128 rows into Al (2 rows per iteration) ----
    const int pair = tid >> 7;                 // 0/1
    const int d    = tid & 127;
    for (int rr = 0; rr < 128; rr += 2) {
        const int row = rr + pair;
        const int m   = m0 + row;
        const int b   = m / S_;
        const int s   = m - b * S_;
        const int len = lengths[b];
        float p = 0.f;
        if (s < len) {
            const int  blen = basket_len[m];
            const int* it   = items + m * K_;
            #pragma unroll 4
            for (int k = 0; k < blen; ++k)
                p += encode[(long)it[k] * D_ + d];
            p /= (float)blen;
        }
        const int dst = (row * 256 + d * 2) ^ ((row & 7) << 4);
        *(unsigned short*)((char*)Al + dst) = bf16_rne(p);
    }
    __syncthreads();

    // ---- A fragments (loaded once) ----
    bf16x8 af[4][KT];
    #pragma unroll
    for (int t = 0; t < 4; ++t) {
        #pragma unroll
        for (int kt = 0; kt < KT; ++kt) {
            int ra = mh + t * 16 + frow;
            int oa = (ra * 256 + kt * 64 + fhi * 16) ^ ((ra & 7) << 4);
            af[t][kt] = *(const bf16x8*)((const char*)Al + oa);
        }
    }

    // ---- phase 2: per gate-tile bn = 0..2 ----
    for (int bn = 0; bn < 3; ++bn) {
        if (bn) __syncthreads();               // all waves done reading Bl
        // stage B tile: f32 -> bf16 inline, swizzled
        #pragma unroll
        for (int i = 0; i < 8; ++i) {
            int idx = tid + i * 256;           // 0..2047
            int row = idx >> 4, c16 = idx & 15;
            const float* wp = w_ih + (long)(bn * 128 + row) * D_ + c16 * 8;
            bf16x8 v;
            #pragma unroll
            for (int j = 0; j < 8; ++j) v[j] = (short)bf16_rne(wp[j]);
            int dst = (row * 256 + c16 * 16) ^ ((row & 7) << 4);
            *(bf16x8*)((char*)Bl + dst) = v;
        }
        __syncthreads();

        bf16x8 bfr[4][KT];
        #pragma unroll
        for (int t = 0; t < 4; ++t) {
            #pragma unroll
            for (int kt = 0; kt < KT; ++kt) {
                int rb = nh + t * 16 + frow;
                int ob = (rb * 256 + kt * 64 + fhi * 16) ^ ((rb & 7) << 4);
                bfr[t][kt] = *(const bf16x8*)((const char*)Bl + ob);
            }
        }

        float bias[4];
        #pragma unroll
        for (int nt = 0; nt < 4; ++nt) {
            int n = bn * 128 + nh + nt * 16 + frow;
            bias[nt] = b_ih[n] + (n < 2 * D_ ? b_hh[n] : 0.f);
        }

        #pragma unroll
        for (int mt = 0; mt < 4; ++mt) {
            #pragma unroll
            for (int nt = 0; nt < 4; ++nt) {
                f32x4 c = {0.f, 0.f, 0.f, 0.f};
                #pragma unroll
                for (int kt = 0; kt < KT; ++kt)
                    c = __builtin_amdgcn_mfma_f32_16x16x32_bf16(af[mt][kt], bfr[nt][kt], c, 0, 0, 0);
                int n = bn * 128 + nh + nt * 16 + frow;
                #pragma unroll
                for (int r = 0; r < 4; ++r) {
                    int row = m0 + mh + mt * 16 + fhi * 4 + r;
                    gx[(long)row * G3 + n] = c[r] + bias[nt];
                }
            }
        }
    }
}

// ---------------------------------------------------------------------------
// Kernel B v10 (R19/R22 proven, 55.7us): gates-in-registers, LDS-only
// barrier, distance-1 named double buffer. Plateau config — unchanged for
// clean attribution of the fusion delta.
// ---------------------------------------------------------------------------
__global__ __launch_bounds__(512, 1) void gru_mfma_kernel(
    const int* __restrict__ lengths, const float* __restrict__ w_hh,
    const float* __restrict__ b_hh, const float* __restrict__ h0,
    const float* __restrict__ gx, float* __restrict__ out)
{
    const int b0   = blockIdx.x * GROWS;
    const int tid  = threadIdx.x;
    const int lane = tid & 63;
    const int wv   = tid >> 6;
    const int frow = lane & 15;
    const int fhi  = lane >> 4;
    const int dim  = wv * 16 + frow;

    __shared__ unsigned short hb[2][GROWS * D_];

    bf16x8 wf[3][KT];
    #pragma unroll
    for (int g = 0; g < 3; ++g) {
        #pragma unroll
        for (int kt = 0; kt < KT; ++kt) {
            const float* wp = w_hh + (g * D_ + dim) * D_ + kt * 32 + fhi * 8;
            bf16x8 v;
            #pragma unroll
            for (int j = 0; j < 8; ++j) v[j] = (short)bf16_rne(wp[j]);
            wf[g][kt] = v;
        }
    }

    const float bhn_s = b_hh[2 * D_ + dim];

    int   mylen[4];
    float hp[4];
    #pragma unroll
    for (int r = 0; r < 4; ++r) {
        int row = fhi * 4 + r;
        mylen[r] = lengths[b0 + row];
        hp[r]    = h0[(long)(b0 + row) * D_ + dim];
        int wb = (row * 256 + dim * 2) ^ ((row & 7) << 4);
        *(unsigned short*)((char*)hb[0] + wb) = bf16_rne(hp[r]);
    }
    const int lenmax = lengths[b0];
    __syncthreads();

    float* ys = out;
    float* hu = out + (long)B_ * S_ * D_;

    const long gxrow[4] = {
        (long)(b0 + fhi * 4 + 0) * S_, (long)(b0 + fhi * 4 + 1) * S_,
        (long)(b0 + fhi * 4 + 2) * S_, (long)(b0 + fhi * 4 + 3) * S_ };

    #define GSTEP(s, CUR, NXT, PP) { \
        const int sn = ((s) + 1 < lenmax) ? (s) + 1 : lenmax - 1; \
        _Pragma("unroll") \
        for (int g = 0; g < 3; ++g) \
            _Pragma("unroll") \
            for (int r = 0; r < 4; ++r) \
                NXT[g][r] = gx[(gxrow[r] + sn) * G3 + g * 128 + dim]; \
        bf16x8 ah[KT]; \
        _Pragma("unroll") \
        for (int kt = 0; kt < KT; ++kt) { \
            int ab = (frow * 256 + kt * 64 + fhi * 16) ^ ((frow & 7) << 4); \
            ah[kt] = *(const bf16x8*)((const char*)hb[PP] + ab); \
        } \
        f32x4 cr = {0.f,0.f,0.f,0.f}, cz = {0.f,0.f,0.f,0.f}, cn = {0.f,0.f,0.f,0.f}; \
        _Pragma("unroll") \
        for (int kt = 0; kt < KT; ++kt) { \
            cr = __builtin_amdgcn_mfma_f32_16x16x32_bf16(ah[kt], wf[0][kt], cr, 0, 0, 0); \
            cz = __builtin_amdgcn_mfma_f32_16x16x32_bf16(ah[kt], wf[1][kt], cz, 0, 0, 0); \
            cn = __builtin_amdgcn_mfma_f32_16x16x32_bf16(ah[kt], wf[2][kt], cn, 0, 0, 0); \
        } \
        _Pragma("unroll") \
        for (int r = 0; r < 4; ++r) { \
            const int row = fhi * 4 + r; \
            const bool act = (s) < mylen[r]; \
            float rg = fsig(CUR[0][r] + cr[r]); \
            float zg = fsig(CUR[1][r] + cz[r]); \
            float ng = ftanh(CUR[2][r] + rg * (cn[r] + bhn_s)); \
            float hn = (1.f - zg) * ng + zg * hp[r]; \
            if (act) { \
                ys[(gxrow[r] + (s)) * D_ + dim] = hn; \
                hp[r] = hn; \
            } \
            int wb = (row * 256 + dim * 2) ^ ((row & 7) << 4); \
            *(unsigned short*)((char*)hb[(PP) ^ 1] + wb) = bf16_rne(hp[r]); \
        } \
        WG_SYNC_LDS(); \
    }

    float curA[3][4], curB[3][4];
    #pragma unroll
    for (int g = 0; g < 3; ++g)
        #pragma unroll
        for (int r = 0; r < 4; ++r)
            curA[g][r] = gx[(gxrow[r] + 0) * G3 + g * 128 + dim];

    int s = 0, pp = 0;
    while (s < lenmax) {
        GSTEP(s, curA, curB, pp);
        ++s; pp ^= 1;
        if (s >= lenmax) break;
        GSTEP(s, curB, curA, pp);
        ++s; pp ^= 1;
    }
    #undef GSTEP

    #pragma unroll
    for (int r = 0; r < 4; ++r) {
        const int row = fhi * 4 + r;
        hu[(long)(b0 + row) * D_ + dim] = hp[r];
        for (int t = mylen[r]; t < S_; ++t)
            ys[((long)(b0 + row) * S_ + t) * D_ + dim] = 0.f;
    }
}

extern "C" void kernel_launch(void* const* d_in, const int* in_sizes, int n_in,
                              void* d_out, int out_size, void* d_ws, size_t ws_size,
                              hipStream_t stream) {
    const int*   items      = (const int*)d_in[0];
    const int*   basket_len = (const int*)d_in[1];
    const int*   lengths    = (const int*)d_in[2];
    const float* encode     = (const float*)d_in[3];
    const float* w_ih       = (const float*)d_in[4];
    const float* w_hh       = (const float*)d_in[5];
    const float* b_ih       = (const float*)d_in[6];
    const float* b_hh       = (const float*)d_in[7];
    const float* h0         = (const float*)d_in[8];
    float* out = (float*)d_out;

    float* gx = (float*)d_ws;   // 12800*384 f32 = 19.66 MB

    pool_gemm_mfma<<<100, 256, 0, stream>>>(
        items, basket_len, lengths, encode, w_ih, b_ih, b_hh, gx);
    gru_mfma_kernel<<<B_ / GROWS, 512, 0, stream>>>(
        lengths, w_hh, b_hh, h0, gx, out);
}

// Round 24
// 79.612 us; speedup vs baseline: 2.6552x; 2.6552x over previous
//
#include <hip/hip_runtime.h>
#include <math.h>

#define B_ 256
#define S_ 50
#define K_ 20
#define D_ 128
#define G3 384          // 3*D
#define M_  (B_ * S_)   // 12800 (b,s) rows
#define GROWS 16        // batch rows per GRU block
#define KT 4            // k-tiles (32 wide): 128

typedef __attribute__((ext_vector_type(8))) short bf16x8;
typedef __attribute__((ext_vector_type(4))) float f32x4;

__device__ inline unsigned short bf16_rne(float f) {
    unsigned u = __float_as_uint(f);
    return (unsigned short)((u + 0x7fffu + ((u >> 16) & 1u)) >> 16);
}
__device__ inline float fsig(float x) {
    return __builtin_amdgcn_rcpf(1.f + __expf(-x));
}
__device__ inline float ftanh(float x) {
    float t = __expf(-2.f * fabsf(x));
    float r = (1.f - t) * __builtin_amdgcn_rcpf(1.f + t);
    return x >= 0.f ? r : -r;
}

#define WG_SYNC_LDS() do { \
    __builtin_amdgcn_sched_barrier(0); \
    asm volatile("s_waitcnt lgkmcnt(0)" ::: "memory"); \
    __builtin_amdgcn_s_barrier(); \
    __builtin_amdgcn_sched_barrier(0); \
} while (0)

// ---------------------------------------------------------------------------
// Kernel P (R22 proven): basket pooling -> bf16, 6400 blocks of pure TLP.
// R23 lesson: fusing this into 100 gemm blocks destroyed the gather's
// latency cover (211us total) — pooling parallelism is sacred.
// ---------------------------------------------------------------------------
__global__ __launch_bounds__(256) void pool_kernel(
    const int* __restrict__ items, const int* __restrict__ basket_len,
    const int* __restrict__ lengths, const float* __restrict__ encode,
    unsigned short* __restrict__ pooled_bf)
{
    const int tid  = threadIdx.x;
    const int pair = tid >> 7;
    const int d    = tid & 127;
    const int m    = blockIdx.x * 2 + pair;
    const int b    = m / S_;
    const int s    = m % S_;
    const int len  = lengths[b];

    float p = 0.f;
    if (s < len) {
        const int  blen = basket_len[m];
        const int* it   = items + m * K_;
        #pragma unroll 4
        for (int k = 0; k < blen; ++k)
            p += encode[(long)it[k] * D_ + d];
        p /= (float)blen;
    }
    pooled_bf[m * D_ + d] = bf16_rne(p);
}

// ---------------------------------------------------------------------------
// Kernel G v4: MFMA GEMM with INLINE w_ih f32->bf16 staging (validated in
// v13 phase 2) — wih_cvt kernel and its round-trip/launch eliminated.
// Standard coalesced gx[row][n] output (R21 relayout regressed; reverted).
// ---------------------------------------------------------------------------
__global__ __launch_bounds__(256) void gx_gemm_mfma(
    const unsigned short* __restrict__ pooled_bf,
    const float* __restrict__ w_ih,
    const float* __restrict__ b_ih, const float* __restrict__ b_hh,
    float* __restrict__ gx)
{
    __shared__ unsigned short Al[128 * 128];   // [m][k] swizzled, 32KB
    __shared__ unsigned short Bl[128 * 128];   // [n][k] swizzled, 32KB

    const int tid  = threadIdx.x;
    const int bm   = blockIdx.x % 100;
    const int bn   = blockIdx.x / 100;         // 0..2
    const int m0   = bm * 128;
    const int n0   = bn * 128;
    const int lane = tid & 63;
    const int wv   = tid >> 6;                 // 0..3
    const int frow = lane & 15;
    const int fhi  = lane >> 4;
    const int mh   = (wv & 1) * 64;
    const int nh   = (wv >> 1) * 64;

    #pragma unroll
    for (int i = 0; i < 8; ++i) {
        int idx = tid + i * 256;               // 0..2047
        int row = idx >> 4, c16 = idx & 15;
        int dst = (row * 256 + c16 * 16) ^ ((row & 7) << 4);
        // A: bf16 from pooled (coalesced 16B)
        *(bf16x8*)((char*)Al + dst) =
            *(const bf16x8*)(pooled_bf + (long)(m0 + row) * D_ + c16 * 8);
        // B: f32 w_ih -> bf16 inline (two float4 loads, coalesced)
        const float* wp = w_ih + (long)(n0 + row) * D_ + c16 * 8;
        bf16x8 v;
        #pragma unroll
        for (int j = 0; j < 8; ++j) v[j] = (short)bf16_rne(wp[j]);
        *(bf16x8*)((char*)Bl + dst) = v;
    }
    __syncthreads();

    bf16x8 af[4][KT], bfr[4][KT];
    #pragma unroll
    for (int t = 0; t < 4; ++t) {
        #pragma unroll
        for (int kt = 0; kt < KT; ++kt) {
            int ra = mh + t * 16 + frow;
            int oa = (ra * 256 + kt * 64 + fhi * 16) ^ ((ra & 7) << 4);
            af[t][kt] = *(const bf16x8*)((const char*)Al + oa);
            int rb = nh + t * 16 + frow;
            int ob = (rb * 256 + kt * 64 + fhi * 16) ^ ((rb & 7) << 4);
            bfr[t][kt] = *(const bf16x8*)((const char*)Bl + ob);
        }
    }

    f32x4 acc[4][4];
    #pragma unroll
    for (int mt = 0; mt < 4; ++mt)
        #pragma unroll
        for (int nt = 0; nt < 4; ++nt) {
            f32x4 c = {0.f, 0.f, 0.f, 0.f};
            #pragma unroll
            for (int kt = 0; kt < KT; ++kt)
                c = __builtin_amdgcn_mfma_f32_16x16x32_bf16(af[mt][kt], bfr[nt][kt], c, 0, 0, 0);
            acc[mt][nt] = c;
        }

    float bias[4];
    #pragma unroll
    for (int nt = 0; nt < 4; ++nt) {
        int n = n0 + nh + nt * 16 + frow;
        bias[nt] = b_ih[n] + (n < 2 * D_ ? b_hh[n] : 0.f);   // fold r/z only
    }

    #pragma unroll
    for (int mt = 0; mt < 4; ++mt) {
        #pragma unroll
        for (int nt = 0; nt < 4; ++nt) {
            int n = n0 + nh + nt * 16 + frow;
            #pragma unroll
            for (int r = 0; r < 4; ++r) {
                int row = m0 + mh + mt * 16 + fhi * 4 + r;
                gx[(long)row * G3 + n] = acc[mt][nt][r] + bias[nt];
            }
        }
    }
}

// ---------------------------------------------------------------------------
// Kernel B v10 (R19/R22 proven, 55.7us): gates-in-registers, LDS-only
// barrier, distance-1 named double buffer. Plateau config (v11 depth-2 and
// v12 relayout both regressed) — unchanged.
// ---------------------------------------------------------------------------
__global__ __launch_bounds__(512, 1) void gru_mfma_kernel(
    const int* __restrict__ lengths, const float* __restrict__ w_hh,
    const float* __restrict__ b_hh, const float* __restrict__ h0,
    const float* __restrict__ gx, float* __restrict__ out)
{
    const int b0   = blockIdx.x * GROWS;
    const int tid  = threadIdx.x;
    const int lane = tid & 63;
    const int wv   = tid >> 6;
    const int frow = lane & 15;
    const int fhi  = lane >> 4;
    const int dim  = wv * 16 + frow;

    __shared__ unsigned short hb[2][GROWS * D_];

    bf16x8 wf[3][KT];
    #pragma unroll
    for (int g = 0; g < 3; ++g) {
        #pragma unroll
        for (int kt = 0; kt < KT; ++kt) {
            const float* wp = w_hh + (g * D_ + dim) * D_ + kt * 32 + fhi * 8;
            bf16x8 v;
            #pragma unroll
            for (int j = 0; j < 8; ++j) v[j] = (short)bf16_rne(wp[j]);
            wf[g][kt] = v;
        }
    }

    const float bhn_s = b_hh[2 * D_ + dim];

    int   mylen[4];
    float hp[4];
    #pragma unroll
    for (int r = 0; r < 4; ++r) {
        int row = fhi * 4 + r;
        mylen[r] = lengths[b0 + row];
        hp[r]    = h0[(long)(b0 + row) * D_ + dim];
        int wb = (row * 256 + dim * 2) ^ ((row & 7) << 4);
        *(unsigned short*)((char*)hb[0] + wb) = bf16_rne(hp[r]);
    }
    const int lenmax = lengths[b0];
    __syncthreads();

    float* ys = out;
    float* hu = out + (long)B_ * S_ * D_;

    const long gxrow[4] = {
        (long)(b0 + fhi * 4 + 0) * S_, (long)(b0 + fhi * 4 + 1) * S_,
        (long)(b0 + fhi * 4 + 2) * S_, (long)(b0 + fhi * 4 + 3) * S_ };

    #define GSTEP(s, CUR, NXT, PP) { \
        const int sn = ((s) + 1 < lenmax) ? (s) + 1 : lenmax - 1; \
        _Pragma("unroll") \
        for (int g = 0; g < 3; ++g) \
            _Pragma("unroll") \
            for (int r = 0; r < 4; ++r) \
                NXT[g][r] = gx[(gxrow[r] + sn) * G3 + g * 128 + dim]; \
        bf16x8 ah[KT]; \
        _Pragma("unroll") \
        for (int kt = 0; kt < KT; ++kt) { \
            int ab = (frow * 256 + kt * 64 + fhi * 16) ^ ((frow & 7) << 4); \
            ah[kt] = *(const bf16x8*)((const char*)hb[PP] + ab); \
        } \
        f32x4 cr = {0.f,0.f,0.f,0.f}, cz = {0.f,0.f,0.f,0.f}, cn = {0.f,0.f,0.f,0.f}; \
        _Pragma("unroll") \
        for (int kt = 0; kt < KT; ++kt) { \
            cr = __builtin_amdgcn_mfma_f32_16x16x32_bf16(ah[kt], wf[0][kt], cr, 0, 0, 0); \
            cz = __builtin_amdgcn_mfma_f32_16x16x32_bf16(ah[kt], wf[1][kt], cz, 0, 0, 0); \
            cn = __builtin_amdgcn_mfma_f32_16x16x32_bf16(ah[kt], wf[2][kt], cn, 0, 0, 0); \
        } \
        _Pragma("unroll") \
        for (int r = 0; r < 4; ++r) { \
            const int row = fhi * 4 + r; \
            const bool act = (s) < mylen[r]; \
            float rg = fsig(CUR[0][r] + cr[r]); \
            float zg = fsig(CUR[1][r] + cz[r]); \
            float ng = ftanh(CUR[2][r] + rg * (cn[r] + bhn_s)); \
            float hn = (1.f - zg) * ng + zg * hp[r]; \
            if (act) { \
                ys[(gxrow[r] + (s)) * D_ + dim] = hn; \
                hp[r] = hn; \
            } \
            int wb = (row * 256 + dim * 2) ^ ((row & 7) << 4); \
            *(unsigned short*)((char*)hb[(PP) ^ 1] + wb) = bf16_rne(hp[r]); \
        } \
        WG_SYNC_LDS(); \
    }

    float curA[3][4], curB[3][4];
    #pragma unroll
    for (int g = 0; g < 3; ++g)
        #pragma unroll
        for (int r = 0; r < 4; ++r)
            curA[g][r] = gx[(gxrow[r] + 0) * G3 + g * 128 + dim];

    int s = 0, pp = 0;
    while (s < lenmax) {
        GSTEP(s, curA, curB, pp);
        ++s; pp ^= 1;
        if (s >= lenmax) break;
        GSTEP(s, curB, curA, pp);
        ++s; pp ^= 1;
    }
    #undef GSTEP

    #pragma unroll
    for (int r = 0; r < 4; ++r) {
        const int row = fhi * 4 + r;
        hu[(long)(b0 + row) * D_ + dim] = hp[r];
        for (int t = mylen[r]; t < S_; ++t)
            ys[((long)(b0 + row) * S_ + t) * D_ + dim] = 0.f;
    }
}

extern "C" void kernel_launch(void* const* d_in, const int* in_sizes, int n_in,
                              void* d_out, int out_size, void* d_ws, size_t ws_size,
                              hipStream_t stream) {
    const int*   items      = (const int*)d_in[0];
    const int*   basket_len = (const int*)d_in[1];
    const int*   lengths    = (const int*)d_in[2];
    const float* encode     = (const float*)d_in[3];
    const float* w_ih       = (const float*)d_in[4];
    const float* w_hh       = (const float*)d_in[5];
    const float* b_ih       = (const float*)d_in[6];
    const float* b_hh       = (const float*)d_in[7];
    const float* h0         = (const float*)d_in[8];
    float* out = (float*)d_out;

    float*          gx        = (float*)d_ws;                    // 19.66 MB
    unsigned short* pooled_bf = (unsigned short*)(gx + (long)M_ * G3);  // 3.28 MB

    pool_kernel<<<M_ / 2, 256, 0, stream>>>(
        items, basket_len, lengths, encode, pooled_bf);
    gx_gemm_mfma<<<300, 256, 0, stream>>>(
        pooled_bf, w_ih, b_ih, b_hh, gx);
    gru_mfma_kernel<<<B_ / GROWS, 512, 0, stream>>>(
        lengths, w_hh, b_hh, h0, gx, out);
}

// Round 25
// 73.931 us; speedup vs baseline: 2.8592x; 1.0768x over previous
//
#include <hip/hip_runtime.h>
#include <math.h>

#define B_ 256
#define S_ 50
#define K_ 20
#define D_ 128
#define G3 384          // 3*D
#define M_  (B_ * S_)   // 12800 (b,s) rows
#define GROWS 16        // batch rows per GRU block
#define KT 4            // k-tiles (32 wide): 128

typedef __attribute__((ext_vector_type(8))) short bf16x8;
typedef __attribute__((ext_vector_type(4))) float f32x4;

__device__ inline unsigned short bf16_rne(float f) {
    unsigned u = __float_as_uint(f);
    return (unsigned short)((u + 0x7fffu + ((u >> 16) & 1u)) >> 16);
}

#define WG_SYNC_LDS() do { \
    __builtin_amdgcn_sched_barrier(0); \
    asm volatile("s_waitcnt lgkmcnt(0)" ::: "memory"); \
    __builtin_amdgcn_s_barrier(); \
    __builtin_amdgcn_sched_barrier(0); \
} while (0)

// ---------------------------------------------------------------------------
// Kernel P (R22 proven): basket pooling -> bf16, 6400 blocks of pure TLP.
// ---------------------------------------------------------------------------
__global__ __launch_bounds__(256) void pool_kernel(
    const int* __restrict__ items, const int* __restrict__ basket_len,
    const int* __restrict__ lengths, const float* __restrict__ encode,
    unsigned short* __restrict__ pooled_bf)
{
    const int tid  = threadIdx.x;
    const int pair = tid >> 7;
    const int d    = tid & 127;
    const int m    = blockIdx.x * 2 + pair;
    const int b    = m / S_;
    const int s    = m % S_;
    const int len  = lengths[b];

    float p = 0.f;
    if (s < len) {
        const int  blen = basket_len[m];
        const int* it   = items + m * K_;
        #pragma unroll 4
        for (int k = 0; k < blen; ++k)
            p += encode[(long)it[k] * D_ + d];
        p /= (float)blen;
    }
    pooled_bf[m * D_ + d] = bf16_rne(p);
}

// ---------------------------------------------------------------------------
// Kernel G v4 (R24 proven): MFMA GEMM with inline w_ih f32->bf16 staging.
// ---------------------------------------------------------------------------
__global__ __launch_bounds__(256) void gx_gemm_mfma(
    const unsigned short* __restrict__ pooled_bf,
    const float* __restrict__ w_ih,
    const float* __restrict__ b_ih, const float* __restrict__ b_hh,
    float* __restrict__ gx)
{
    __shared__ unsigned short Al[128 * 128];   // [m][k] swizzled, 32KB
    __shared__ unsigned short Bl[128 * 128];   // [n][k] swizzled, 32KB

    const int tid  = threadIdx.x;
    const int bm   = blockIdx.x % 100;
    const int bn   = blockIdx.x / 100;         // 0..2
    const int m0   = bm * 128;
    const int n0   = bn * 128;
    const int lane = tid & 63;
    const int wv   = tid >> 6;                 // 0..3
    const int frow = lane & 15;
    const int fhi  = lane >> 4;
    const int mh   = (wv & 1) * 64;
    const int nh   = (wv >> 1) * 64;

    #pragma unroll
    for (int i = 0; i < 8; ++i) {
        int idx = tid + i * 256;               // 0..2047
        int row = idx >> 4, c16 = idx & 15;
        int dst = (row * 256 + c16 * 16) ^ ((row & 7) << 4);
        *(bf16x8*)((char*)Al + dst) =
            *(const bf16x8*)(pooled_bf + (long)(m0 + row) * D_ + c16 * 8);
        const float* wp = w_ih + (long)(n0 + row) * D_ + c16 * 8;
        bf16x8 v;
        #pragma unroll
        for (int j = 0; j < 8; ++j) v[j] = (short)bf16_rne(wp[j]);
        *(bf16x8*)((char*)Bl + dst) = v;
    }
    __syncthreads();

    bf16x8 af[4][KT], bfr[4][KT];
    #pragma unroll
    for (int t = 0; t < 4; ++t) {
        #pragma unroll
        for (int kt = 0; kt < KT; ++kt) {
            int ra = mh + t * 16 + frow;
            int oa = (ra * 256 + kt * 64 + fhi * 16) ^ ((ra & 7) << 4);
            af[t][kt] = *(const bf16x8*)((const char*)Al + oa);
            int rb = nh + t * 16 + frow;
            int ob = (rb * 256 + kt * 64 + fhi * 16) ^ ((rb & 7) << 4);
            bfr[t][kt] = *(const bf16x8*)((const char*)Bl + ob);
        }
    }

    f32x4 acc[4][4];
    #pragma unroll
    for (int mt = 0; mt < 4; ++mt)
        #pragma unroll
        for (int nt = 0; nt < 4; ++nt) {
            f32x4 c = {0.f, 0.f, 0.f, 0.f};
            #pragma unroll
            for (int kt = 0; kt < KT; ++kt)
                c = __builtin_amdgcn_mfma_f32_16x16x32_bf16(af[mt][kt], bfr[nt][kt], c, 0, 0, 0);
            acc[mt][nt] = c;
        }

    float bias[4];
    #pragma unroll
    for (int nt = 0; nt < 4; ++nt) {
        int n = n0 + nh + nt * 16 + frow;
        bias[nt] = b_ih[n] + (n < 2 * D_ ? b_hh[n] : 0.f);   // fold r/z only
    }

    #pragma unroll
    for (int mt = 0; mt < 4; ++mt) {
        #pragma unroll
        for (int nt = 0; nt < 4; ++nt) {
            int n = n0 + nh + nt * 16 + frow;
            #pragma unroll
            for (int r = 0; r < 4; ++r) {
                int row = m0 + mh + mt * 16 + fhi * 4 + r;
                gx[(long)row * G3 + n] = acc[mt][nt][r] + bias[nt];
            }
        }
    }
}

// ---------------------------------------------------------------------------
// Kernel B v14: v10 + leaner gates. R24 analysis: per-active-CU VALUBusy 33%
// with 24 quarter-rate trans/lane/step — trim the trans/VALU issue:
//   - shared rcp for r,z:  inv=rcp((1+a)(1+b)); rg=(1+b)inv; zg=(1+a)inv
//   - branch-free tanh:    tanh(x) = 1 - 2/(1+e^{2x})  (saturates in f32)
//   - hn = fma(zg, hp-ng, ng)
// Pre-commit: flat result => step is barrier/skew-bound => GRU declared done.
// ---------------------------------------------------------------------------
__global__ __launch_bounds__(512, 1) void gru_mfma_kernel(
    const int* __restrict__ lengths, const float* __restrict__ w_hh,
    const float* __restrict__ b_hh, const float* __restrict__ h0,
    const float* __restrict__ gx, float* __restrict__ out)
{
    const int b0   = blockIdx.x * GROWS;
    const int tid  = threadIdx.x;
    const int lane = tid & 63;
    const int wv   = tid >> 6;
    const int frow = lane & 15;
    const int fhi  = lane >> 4;
    const int dim  = wv * 16 + frow;

    __shared__ unsigned short hb[2][GROWS * D_];

    bf16x8 wf[3][KT];
    #pragma unroll
    for (int g = 0; g < 3; ++g) {
        #pragma unroll
        for (int kt = 0; kt < KT; ++kt) {
            const float* wp = w_hh + (g * D_ + dim) * D_ + kt * 32 + fhi * 8;
            bf16x8 v;
            #pragma unroll
            for (int j = 0; j < 8; ++j) v[j] = (short)bf16_rne(wp[j]);
            wf[g][kt] = v;
        }
    }

    const float bhn_s = b_hh[2 * D_ + dim];

    int   mylen[4];
    float hp[4];
    #pragma unroll
    for (int r = 0; r < 4; ++r) {
        int row = fhi * 4 + r;
        mylen[r] = lengths[b0 + row];
        hp[r]    = h0[(long)(b0 + row) * D_ + dim];
        int wb = (row * 256 + dim * 2) ^ ((row & 7) << 4);
        *(unsigned short*)((char*)hb[0] + wb) = bf16_rne(hp[r]);
    }
    const int lenmax = lengths[b0];
    __syncthreads();

    float* ys = out;
    float* hu = out + (long)B_ * S_ * D_;

    const long gxrow[4] = {
        (long)(b0 + fhi * 4 + 0) * S_, (long)(b0 + fhi * 4 + 1) * S_,
        (long)(b0 + fhi * 4 + 2) * S_, (long)(b0 + fhi * 4 + 3) * S_ };

    #define GSTEP(s, CUR, NXT, PP) { \
        const int sn = ((s) + 1 < lenmax) ? (s) + 1 : lenmax - 1; \
        _Pragma("unroll") \
        for (int g = 0; g < 3; ++g) \
            _Pragma("unroll") \
            for (int r = 0; r < 4; ++r) \
                NXT[g][r] = gx[(gxrow[r] + sn) * G3 + g * 128 + dim]; \
        bf16x8 ah[KT]; \
        _Pragma("unroll") \
        for (int kt = 0; kt < KT; ++kt) { \
            int ab = (frow * 256 + kt * 64 + fhi * 16) ^ ((frow & 7) << 4); \
            ah[kt] = *(const bf16x8*)((const char*)hb[PP] + ab); \
        } \
        f32x4 cr = {0.f,0.f,0.f,0.f}, cz = {0.f,0.f,0.f,0.f}, cn = {0.f,0.f,0.f,0.f}; \
        _Pragma("unroll") \
        for (int kt = 0; kt < KT; ++kt) { \
            cr = __builtin_amdgcn_mfma_f32_16x16x32_bf16(ah[kt], wf[0][kt], cr, 0, 0, 0); \
            cz = __builtin_amdgcn_mfma_f32_16x16x32_bf16(ah[kt], wf[1][kt], cz, 0, 0, 0); \
            cn = __builtin_amdgcn_mfma_f32_16x16x32_bf16(ah[kt], wf[2][kt], cn, 0, 0, 0); \
        } \
        _Pragma("unroll") \
        for (int r = 0; r < 4; ++r) { \
            const int row = fhi * 4 + r; \
            const bool act = (s) < mylen[r]; \
            float a  = __expf(-(CUR[0][r] + cr[r])); \
            float bb = __expf(-(CUR[1][r] + cz[r])); \
            float inv = __builtin_amdgcn_rcpf((1.f + a) * (1.f + bb)); \
            float rg = (1.f + bb) * inv; \
            float zg = (1.f + a) * inv; \
            float xx = fmaf(rg, cn[r] + bhn_s, CUR[2][r]); \
            float tt = __expf(2.f * xx); \
            float ng = fmaf(-2.f, __builtin_amdgcn_rcpf(1.f + tt), 1.f); \
            float hn = fmaf(zg, hp[r] - ng, ng); \
            if (act) { \
                ys[(gxrow[r] + (s)) * D_ + dim] = hn; \
                hp[r] = hn; \
            } \
            int wb = (row * 256 + dim * 2) ^ ((row & 7) << 4); \
            *(unsigned short*)((char*)hb[(PP) ^ 1] + wb) = bf16_rne(hp[r]); \
        } \
        WG_SYNC_LDS(); \
    }

    float curA[3][4], curB[3][4];
    #pragma unroll
    for (int g = 0; g < 3; ++g)
        #pragma unroll
        for (int r = 0; r < 4; ++r)
            curA[g][r] = gx[(gxrow[r] + 0) * G3 + g * 128 + dim];

    int s = 0, pp = 0;
    while (s < lenmax) {
        GSTEP(s, curA, curB, pp);
        ++s; pp ^= 1;
        if (s >= lenmax) break;
        GSTEP(s, curB, curA, pp);
        ++s; pp ^= 1;
    }
    #undef GSTEP

    #pragma unroll
    for (int r = 0; r < 4; ++r) {
        const int row = fhi * 4 + r;
        hu[(long)(b0 + row) * D_ + dim] = hp[r];
        for (int t = mylen[r]; t < S_; ++t)
            ys[((long)(b0 + row) * S_ + t) * D_ + dim] = 0.f;
    }
}

extern "C" void kernel_launch(void* const* d_in, const int* in_sizes, int n_in,
                              void* d_out, int out_size, void* d_ws, size_t ws_size,
                              hipStream_t stream) {
    const int*   items      = (const int*)d_in[0];
    const int*   basket_len = (const int*)d_in[1];
    const int*   lengths    = (const int*)d_in[2];
    const float* encode     = (const float*)d_in[3];
    const float* w_ih       = (const float*)d_in[4];
    const float* w_hh       = (const float*)d_in[5];
    const float* b_ih       = (const float*)d_in[6];
    const float* b_hh       = (const float*)d_in[7];
    const float* h0         = (const float*)d_in[8];
    float* out = (float*)d_out;

    float*          gx        = (float*)d_ws;                    // 19.66 MB
    unsigned short* pooled_bf = (unsigned short*)(gx + (long)M_ * G3);  // 3.28 MB

    pool_kernel<<<M_ / 2, 256, 0, stream>>>(
        items, basket_len, lengths, encode, pooled_bf);
    gx_gemm_mfma<<<300, 256, 0, stream>>>(
        pooled_bf, w_ih, b_ih, b_hh, gx);
    gru_mfma_kernel<<<B_ / GROWS, 512, 0, stream>>>(
        lengths, w_hh, b_hh, h0, gx, out);
}

// Round 26
// 71.292 us; speedup vs baseline: 2.9651x; 1.0370x over previous
//
#include <hip/hip_runtime.h>
#include <math.h>

#define B_ 256
#define S_ 50
#define K_ 20
#define D_ 128
#define G3 384          // 3*D
#define M_  (B_ * S_)   // 12800 (b,s) rows
#define GROWS 16        // batch rows per GRU block
#define KT 4            // k-tiles (32 wide): 128

typedef __attribute__((ext_vector_type(8))) short bf16x8;
typedef __attribute__((ext_vector_type(4))) float f32x4;

__device__ inline unsigned short bf16_rne(float f) {
    unsigned u = __float_as_uint(f);
    return (unsigned short)((u + 0x7fffu + ((u >> 16) & 1u)) >> 16);
}

#define WG_SYNC_LDS() do { \
    __builtin_amdgcn_sched_barrier(0); \
    asm volatile("s_waitcnt lgkmcnt(0)" ::: "memory"); \
    __builtin_amdgcn_s_barrier(); \
    __builtin_amdgcn_sched_barrier(0); \
} while (0)

// ---------------------------------------------------------------------------
// Kernel P v2: basket pooling, float2 (8B/lane, G13) — 64 lanes per (b,s)
// row, 4 rows/block, 3200 blocks. Halves gather instruction count vs the
// 4B/lane version; same f32 add order per element (absmax-identical).
// ---------------------------------------------------------------------------
__global__ __launch_bounds__(256) void pool_kernel(
    const int* __restrict__ items, const int* __restrict__ basket_len,
    const int* __restrict__ lengths, const float* __restrict__ encode,
    unsigned short* __restrict__ pooled_bf)
{
    const int tid = threadIdx.x;
    const int sub = tid >> 6;          // 0..3: row within block
    const int d2  = tid & 63;          // float2 index within row
    const int m   = blockIdx.x * 4 + sub;
    const int b   = m / S_;
    const int s   = m % S_;
    const int len = lengths[b];

    float px = 0.f, py = 0.f;
    if (s < len) {
        const int  blen = basket_len[m];
        const int* it   = items + m * K_;
        #pragma unroll 4
        for (int k = 0; k < blen; ++k) {
            float2 e = *(const float2*)(encode + (long)it[k] * D_ + d2 * 2);
            px += e.x; py += e.y;
        }
        px /= (float)blen; py /= (float)blen;
    }
    unsigned short lo = bf16_rne(px), hi = bf16_rne(py);
    *(unsigned*)(pooled_bf + m * D_ + d2 * 2) = (unsigned)lo | ((unsigned)hi << 16);
}

// ---------------------------------------------------------------------------
// Kernel G v4 (R24 proven): MFMA GEMM with inline w_ih f32->bf16 staging.
// ---------------------------------------------------------------------------
__global__ __launch_bounds__(256) void gx_gemm_mfma(
    const unsigned short* __restrict__ pooled_bf,
    const float* __restrict__ w_ih,
    const float* __restrict__ b_ih, const float* __restrict__ b_hh,
    float* __restrict__ gx)
{
    __shared__ unsigned short Al[128 * 128];   // [m][k] swizzled, 32KB
    __shared__ unsigned short Bl[128 * 128];   // [n][k] swizzled, 32KB

    const int tid  = threadIdx.x;
    const int bm   = blockIdx.x % 100;
    const int bn   = blockIdx.x / 100;         // 0..2
    const int m0   = bm * 128;
    const int n0   = bn * 128;
    const int lane = tid & 63;
    const int wv   = tid >> 6;                 // 0..3
    const int frow = lane & 15;
    const int fhi  = lane >> 4;
    const int mh   = (wv & 1) * 64;
    const int nh   = (wv >> 1) * 64;

    #pragma unroll
    for (int i = 0; i < 8; ++i) {
        int idx = tid + i * 256;               // 0..2047
        int row = idx >> 4, c16 = idx & 15;
        int dst = (row * 256 + c16 * 16) ^ ((row & 7) << 4);
        *(bf16x8*)((char*)Al + dst) =
            *(const bf16x8*)(pooled_bf + (long)(m0 + row) * D_ + c16 * 8);
        const float* wp = w_ih + (long)(n0 + row) * D_ + c16 * 8;
        bf16x8 v;
        #pragma unroll
        for (int j = 0; j < 8; ++j) v[j] = (short)bf16_rne(wp[j]);
        *(bf16x8*)((char*)Bl + dst) = v;
    }
    __syncthreads();

    bf16x8 af[4][KT], bfr[4][KT];
    #pragma unroll
    for (int t = 0; t < 4; ++t) {
        #pragma unroll
        for (int kt = 0; kt < KT; ++kt) {
            int ra = mh + t * 16 + frow;
            int oa = (ra * 256 + kt * 64 + fhi * 16) ^ ((ra & 7) << 4);
            af[t][kt] = *(const bf16x8*)((const char*)Al + oa);
            int rb = nh + t * 16 + frow;
            int ob = (rb * 256 + kt * 64 + fhi * 16) ^ ((rb & 7) << 4);
            bfr[t][kt] = *(const bf16x8*)((const char*)Bl + ob);
        }
    }

    f32x4 acc[4][4];
    #pragma unroll
    for (int mt = 0; mt < 4; ++mt)
        #pragma unroll
        for (int nt = 0; nt < 4; ++nt) {
            f32x4 c = {0.f, 0.f, 0.f, 0.f};
            #pragma unroll
            for (int kt = 0; kt < KT; ++kt)
                c = __builtin_amdgcn_mfma_f32_16x16x32_bf16(af[mt][kt], bfr[nt][kt], c, 0, 0, 0);
            acc[mt][nt] = c;
        }

    float bias[4];
    #pragma unroll
    for (int nt = 0; nt < 4; ++nt) {
        int n = n0 + nh + nt * 16 + frow;
        bias[nt] = b_ih[n] + (n < 2 * D_ ? b_hh[n] : 0.f);   // fold r/z only
    }

    #pragma unroll
    for (int mt = 0; mt < 4; ++mt) {
        #pragma unroll
        for (int nt = 0; nt < 4; ++nt) {
            int n = n0 + nh + nt * 16 + frow;
            #pragma unroll
            for (int r = 0; r < 4; ++r) {
                int row = m0 + mh + mt * 16 + fhi * 4 + r;
                gx[(long)row * G3 + n] = acc[mt][nt][r] + bias[nt];
            }
        }
    }
}

// ---------------------------------------------------------------------------
// Kernel B v14 (R25 proven, 49.9us): gates-in-registers MFMA GRU, LDS-only
// barrier, distance-1 named double buffer, lean gates (shared rcp, branch-
// free tanh, fma update). Plateau config — unchanged.
// ---------------------------------------------------------------------------
__global__ __launch_bounds__(512, 1) void gru_mfma_kernel(
    const int* __restrict__ lengths, const float* __restrict__ w_hh,
    const float* __restrict__ b_hh, const float* __restrict__ h0,
    const float* __restrict__ gx, float* __restrict__ out)
{
    const int b0   = blockIdx.x * GROWS;
    const int tid  = threadIdx.x;
    const int lane = tid & 63;
    const int wv   = tid >> 6;
    const int frow = lane & 15;
    const int fhi  = lane >> 4;
    const int dim  = wv * 16 + frow;

    __shared__ unsigned short hb[2][GROWS * D_];

    bf16x8 wf[3][KT];
    #pragma unroll
    for (int g = 0; g < 3; ++g) {
        #pragma unroll
        for (int kt = 0; kt < KT; ++kt) {
            const float* wp = w_hh + (g * D_ + dim) * D_ + kt * 32 + fhi * 8;
            bf16x8 v;
            #pragma unroll
            for (int j = 0; j < 8; ++j) v[j] = (short)bf16_rne(wp[j]);
            wf[g][kt] = v;
        }
    }

    const float bhn_s = b_hh[2 * D_ + dim];

    int   mylen[4];
    float hp[4];
    #pragma unroll
    for (int r = 0; r < 4; ++r) {
        int row = fhi * 4 + r;
        mylen[r] = lengths[b0 + row];
        hp[r]    = h0[(long)(b0 + row) * D_ + dim];
        int wb = (row * 256 + dim * 2) ^ ((row & 7) << 4);
        *(unsigned short*)((char*)hb[0] + wb) = bf16_rne(hp[r]);
    }
    const int lenmax = lengths[b0];
    __syncthreads();

    float* ys = out;
    float* hu = out + (long)B_ * S_ * D_;

    const long gxrow[4] = {
        (long)(b0 + fhi * 4 + 0) * S_, (long)(b0 + fhi * 4 + 1) * S_,
        (long)(b0 + fhi * 4 + 2) * S_, (long)(b0 + fhi * 4 + 3) * S_ };

    #define GSTEP(s, CUR, NXT, PP) { \
        const int sn = ((s) + 1 < lenmax) ? (s) + 1 : lenmax - 1; \
        _Pragma("unroll") \
        for (int g = 0; g < 3; ++g) \
            _Pragma("unroll") \
            for (int r = 0; r < 4; ++r) \
                NXT[g][r] = gx[(gxrow[r] + sn) * G3 + g * 128 + dim]; \
        bf16x8 ah[KT]; \
        _Pragma("unroll") \
        for (int kt = 0; kt < KT; ++kt) { \
            int ab = (frow * 256 + kt * 64 + fhi * 16) ^ ((frow & 7) << 4); \
            ah[kt] = *(const bf16x8*)((const char*)hb[PP] + ab); \
        } \
        f32x4 cr = {0.f,0.f,0.f,0.f}, cz = {0.f,0.f,0.f,0.f}, cn = {0.f,0.f,0.f,0.f}; \
        _Pragma("unroll") \
        for (int kt = 0; kt < KT; ++kt) { \
            cr = __builtin_amdgcn_mfma_f32_16x16x32_bf16(ah[kt], wf[0][kt], cr, 0, 0, 0); \
            cz = __builtin_amdgcn_mfma_f32_16x16x32_bf16(ah[kt], wf[1][kt], cz, 0, 0, 0); \
            cn = __builtin_amdgcn_mfma_f32_16x16x32_bf16(ah[kt], wf[2][kt], cn, 0, 0, 0); \
        } \
        _Pragma("unroll") \
        for (int r = 0; r < 4; ++r) { \
            const int row = fhi * 4 + r; \
            const bool act = (s) < mylen[r]; \
            float a  = __expf(-(CUR[0][r] + cr[r])); \
            float bb = __expf(-(CUR[1][r] + cz[r])); \
            float inv = __builtin_amdgcn_rcpf((1.f + a) * (1.f + bb)); \
            float rg = (1.f + bb) * inv; \
            float zg = (1.f + a) * inv; \
            float xx = fmaf(rg, cn[r] + bhn_s, CUR[2][r]); \
            float tt = __expf(2.f * xx); \
            float ng = fmaf(-2.f, __builtin_amdgcn_rcpf(1.f + tt), 1.f); \
            float hn = fmaf(zg, hp[r] - ng, ng); \
            if (act) { \
                ys[(gxrow[r] + (s)) * D_ + dim] = hn; \
                hp[r] = hn; \
            } \
            int wb = (row * 256 + dim * 2) ^ ((row & 7) << 4); \
            *(unsigned short*)((char*)hb[(PP) ^ 1] + wb) = bf16_rne(hp[r]); \
        } \
        WG_SYNC_LDS(); \
    }

    float curA[3][4], curB[3][4];
    #pragma unroll
    for (int g = 0; g < 3; ++g)
        #pragma unroll
        for (int r = 0; r < 4; ++r)
            curA[g][r] = gx[(gxrow[r] + 0) * G3 + g * 128 + dim];

    int s = 0, pp = 0;
    while (s < lenmax) {
        GSTEP(s, curA, curB, pp);
        ++s; pp ^= 1;
        if (s >= lenmax) break;
        GSTEP(s, curB, curA, pp);
        ++s; pp ^= 1;
    }
    #undef GSTEP

    #pragma unroll
    for (int r = 0; r < 4; ++r) {
        const int row = fhi * 4 + r;
        hu[(long)(b0 + row) * D_ + dim] = hp[r];
        for (int t = mylen[r]; t < S_; ++t)
            ys[((long)(b0 + row) * S_ + t) * D_ + dim] = 0.f;
    }
}

extern "C" void kernel_launch(void* const* d_in, const int* in_sizes, int n_in,
                              void* d_out, int out_size, void* d_ws, size_t ws_size,
                              hipStream_t stream) {
    const int*   items      = (const int*)d_in[0];
    const int*   basket_len = (const int*)d_in[1];
    const int*   lengths    = (const int*)d_in[2];
    const float* encode     = (const float*)d_in[3];
    const float* w_ih       = (const float*)d_in[4];
    const float* w_hh       = (const float*)d_in[5];
    const float* b_ih       = (const float*)d_in[6];
    const float* b_hh       = (const float*)d_in[7];
    const float* h0         = (const float*)d_in[8];
    float* out = (float*)d_out;

    float*          gx        = (float*)d_ws;                    // 19.66 MB
    unsigned short* pooled_bf = (unsigned short*)(gx + (long)M_ * G3);  // 3.28 MB

    pool_kernel<<<M_ / 4, 256, 0, stream>>>(
        items, basket_len, lengths, encode, pooled_bf);
    gx_gemm_mfma<<<300, 256, 0, stream>>>(
        pooled_bf, w_ih, b_ih, b_hh, gx);
    gru_mfma_kernel<<<B_ / GROWS, 512, 0, stream>>>(
        lengths, w_hh, b_hh, h0, gx, out);
}